// Round 1
// baseline (1716.200 us; speedup 1.0000x reference)
//
#include <hip/hip_runtime.h>
#include <math.h>

#define BDIM 8
#define FR   257
#define TT   300
#define CC   64
#define NN   (BDIM*TT)      // 2400
#define CPPC 16
#define GG   8
#define CPG  8              // CC/GG
#define KW   3
#define EPSV 1e-5f
#define FSTR 65             // padded LDS row stride (floats)

#define X1_ELEMS ((size_t)NN*FR*CC)     // 39,475,200
#define HP_ELEMS ((size_t)CPPC*NN*FR)   //  9,868,800

// ---------------- Kernel 1: freq_conv1 + LN2 + reduce + silu ----------------
__global__ __launch_bounds__(256, 1)
void k_fc1(const float* __restrict__ h,
           const float* __restrict__ g1, const float* __restrict__ b1,
           const float* __restrict__ w1, const float* __restrict__ cb1,
           const float* __restrict__ a1,
           const float* __restrict__ g2, const float* __restrict__ b2,
           const float* __restrict__ redw, const float* __restrict__ redb,
           float* __restrict__ x1, float* __restrict__ hpT)
{
    __shared__ float xs[FR*FSTR];
    __shared__ float ys[FR*FSTR];
    __shared__ float rw[CPPC*CC];
    __shared__ float rb[CPPC];

    const int n = blockIdx.x;
    const int b = n / TT, t = n - b*TT;
    const int tid = threadIdx.x;
    const int lane = tid & 63, wid = tid >> 6;

    // per-lane params (lane == channel)
    float wreg[CPG][KW];
    #pragma unroll
    for (int i = 0; i < CPG; ++i)
        #pragma unroll
        for (int k = 0; k < KW; ++k)
            wreg[i][k] = w1[lane*CPG*KW + i*KW + k];
    const float alpha = a1[0];
    const float gA = g1[lane], bA = b1[lane];
    const float gB = g2[lane], bB = b2[lane];
    const float cbv = cb1[lane];

    for (int e = tid; e < CPPC*CC; e += 256) rw[e] = redw[e];
    if (tid < CPPC) rb[tid] = redb[tid];

    // load h row slice [F, C]  (h layout: [B, FR, TT, CC])
    const int hbase = ((b*FR)*TT + t)*CC;
    for (int e = tid; e < FR*CC; e += 256) {
        int f = e >> 6, c = e & 63;
        xs[f*FSTR + c] = h[hbase + f*TT*CC + c];
    }
    __syncthreads();

    // LN1 per row (wave = row, lane = channel)
    for (int f = wid; f < FR; f += 4) {
        float v = xs[f*FSTR + lane];
        float s = v, ss = v*v;
        #pragma unroll
        for (int off = 32; off > 0; off >>= 1) {
            s  += __shfl_xor(s,  off, 64);
            ss += __shfl_xor(ss, off, 64);
        }
        float m = s * (1.0f/64.0f);
        float var = ss * (1.0f/64.0f) - m*m;
        float r = rsqrtf(var + EPSV);
        ys[f*FSTR + lane] = (v - m) * r * gA + bA;
    }
    __syncthreads();

    // grouped conv over F (K=3, pad 1) + PReLU + residual
    const int gi = (lane >> 3) * CPG;
    for (int f = wid; f < FR; f += 4) {
        float acc = cbv;
        #pragma unroll
        for (int k = 0; k < KW; ++k) {
            int fs = f + k - 1;
            if (fs >= 0 && fs < FR) {
                #pragma unroll
                for (int i = 0; i < CPG; ++i)
                    acc += ys[fs*FSTR + gi + i] * wreg[i][k];
            }
        }
        float pr = acc >= 0.0f ? acc : alpha*acc;
        float xv = xs[f*FSTR + lane] + pr;
        xs[f*FSTR + lane] = xv;                 // safe: conv reads only ys
        x1[(size_t)n*FR*CC + f*CC + lane] = xv;
    }
    __syncthreads();

    // LN2 (full-band LN) per row -> ys
    for (int f = wid; f < FR; f += 4) {
        float v = xs[f*FSTR + lane];
        float s = v, ss = v*v;
        #pragma unroll
        for (int off = 32; off > 0; off >>= 1) {
            s  += __shfl_xor(s,  off, 64);
            ss += __shfl_xor(ss, off, 64);
        }
        float m = s * (1.0f/64.0f);
        float var = ss * (1.0f/64.0f) - m*m;
        float r = rsqrtf(var + EPSV);
        ys[f*FSTR + lane] = (v - m) * r * gB + bB;
    }
    __syncthreads();

    // reduce: hp[p, f] = silu( sum_c ys[f,c]*rw[p,c] + rb[p] ) -> hpT[p][n][f]
    for (int e = tid; e < CPPC*FR; e += 256) {
        int p = e / FR, f = e - p*FR;
        float acc = rb[p];
        const float* yrow = &ys[f*FSTR];
        const float* wrow = &rw[p*CC];
        #pragma unroll 8
        for (int c = 0; c < CC; ++c) acc += yrow[c] * wrow[c];
        float sg = acc / (1.0f + expf(-acc));
        hpT[(size_t)p*(NN*FR) + (size_t)n*FR + f] = sg;
    }
}

// ---------------- Kernel 2: 16 batched GEMMs  out[n,f'] = sum_f A[n,f]*B[f',f] ----------------
#define BM 64
#define BN 64
#define BK 32
#define LDT 72   // padded LDS stride: 288 B, 16B-aligned, bank-spread

__global__ __launch_bounds__(256, 2)
void k_fgemm(const float* __restrict__ hpT, const float* __restrict__ fW,
             const float* __restrict__ fB, float* __restrict__ hp2T)
{
    __shared__ __align__(16) float As[BK*LDT];
    __shared__ __align__(16) float Bs[BK*LDT];
    const int c  = blockIdx.z;
    const int m0 = blockIdx.x * BM;
    const int f0 = blockIdx.y * BN;
    const int tid = threadIdx.x;
    const int tm = tid & 15, tn = tid >> 4;

    const float* Ab = hpT + (size_t)c*(NN*FR);
    const float* Bb = fW  + (size_t)c*(FR*FR);

    float acc[4][4];
    #pragma unroll
    for (int i = 0; i < 4; ++i)
        #pragma unroll
        for (int j = 0; j < 4; ++j) acc[i][j] = 0.0f;

    for (int k0 = 0; k0 < FR; k0 += BK) {
        #pragma unroll
        for (int l = 0; l < 8; ++l) {
            int e = tid + l*256;
            int r = e >> 5, kc = e & 31;
            int m = m0 + r, k = k0 + kc;
            As[kc*LDT + r] = (m < NN && k < FR) ? Ab[(size_t)m*FR + k] : 0.0f;
            int fr = f0 + r;
            Bs[kc*LDT + r] = (fr < FR && k < FR) ? Bb[(size_t)fr*FR + k] : 0.0f;
        }
        __syncthreads();
        #pragma unroll
        for (int k = 0; k < BK; ++k) {
            const float4 av = *reinterpret_cast<const float4*>(&As[k*LDT + (tm<<2)]);
            const float4 bv = *reinterpret_cast<const float4*>(&Bs[k*LDT + (tn<<2)]);
            acc[0][0] += av.x*bv.x; acc[0][1] += av.x*bv.y; acc[0][2] += av.x*bv.z; acc[0][3] += av.x*bv.w;
            acc[1][0] += av.y*bv.x; acc[1][1] += av.y*bv.y; acc[1][2] += av.y*bv.z; acc[1][3] += av.y*bv.w;
            acc[2][0] += av.z*bv.x; acc[2][1] += av.z*bv.y; acc[2][2] += av.z*bv.z; acc[2][3] += av.z*bv.w;
            acc[3][0] += av.w*bv.x; acc[3][1] += av.w*bv.y; acc[3][2] += av.w*bv.z; acc[3][3] += av.w*bv.w;
        }
        __syncthreads();
    }

    #pragma unroll
    for (int i = 0; i < 4; ++i) {
        int m = m0 + (tm<<2) + i;
        if (m >= NN) continue;
        #pragma unroll
        for (int j = 0; j < 4; ++j) {
            int fr = f0 + (tn<<2) + j;
            if (fr < FR)
                hp2T[(size_t)c*(NN*FR) + (size_t)m*FR + fr] = acc[i][j] + fB[c*FR + fr];
        }
    }
}

// ---------------- Kernel 3: expand + silu + residual + freq_conv2 ----------------
__global__ __launch_bounds__(256, 1)
void k_fc2(const float* __restrict__ x1, const float* __restrict__ hp2T,
           const float* __restrict__ expw, const float* __restrict__ expb,
           const float* __restrict__ g3, const float* __restrict__ b3,
           const float* __restrict__ w2, const float* __restrict__ cb2,
           const float* __restrict__ a2,
           float* __restrict__ out)
{
    __shared__ float xs[FR*FSTR];
    __shared__ float ys[FR*FSTR];
    __shared__ float hb[CPPC*FR];

    const int n = blockIdx.x;
    const int b = n / TT, t = n - b*TT;
    const int tid = threadIdx.x;
    const int lane = tid & 63, wid = tid >> 6;

    float wreg[CPG][KW];
    #pragma unroll
    for (int i = 0; i < CPG; ++i)
        #pragma unroll
        for (int k = 0; k < KW; ++k)
            wreg[i][k] = w2[lane*CPG*KW + i*KW + k];
    float ew[CPPC];
    #pragma unroll
    for (int p = 0; p < CPPC; ++p) ew[p] = expw[lane*CPPC + p];
    const float ebv = expb[lane];
    const float gC = g3[lane], bC = b3[lane];
    const float alpha = a2[0];
    const float cbv = cb2[lane];

    for (int e = tid; e < CPPC*FR; e += 256) {
        int p = e / FR, f = e - p*FR;
        hb[e] = hp2T[(size_t)p*(NN*FR) + (size_t)n*FR + f];
    }
    for (int e = tid; e < FR*CC; e += 256) {
        int f = e >> 6, c = e & 63;
        xs[f*FSTR + c] = x1[(size_t)n*FR*CC + e];
    }
    __syncthreads();

    // expand + silu + residual -> x2 (in xs), then LN3 -> ys
    for (int f = wid; f < FR; f += 4) {
        float z = ebv;
        #pragma unroll
        for (int p = 0; p < CPPC; ++p) z += hb[p*FR + f] * ew[p];
        float sg = z / (1.0f + expf(-z));
        float v = xs[f*FSTR + lane] + sg;

        float s = v, ss = v*v;
        #pragma unroll
        for (int off = 32; off > 0; off >>= 1) {
            s  += __shfl_xor(s,  off, 64);
            ss += __shfl_xor(ss, off, 64);
        }
        float m = s * (1.0f/64.0f);
        float var = ss * (1.0f/64.0f) - m*m;
        float r = rsqrtf(var + EPSV);
        ys[f*FSTR + lane] = (v - m) * r * gC + bC;
        xs[f*FSTR + lane] = v;
    }
    __syncthreads();

    // conv2 + PReLU + residual -> out in [B, FR, TT, CC] layout
    const int gi = (lane >> 3) * CPG;
    const int obase = ((b*FR)*TT + t)*CC;
    for (int f = wid; f < FR; f += 4) {
        float acc = cbv;
        #pragma unroll
        for (int k = 0; k < KW; ++k) {
            int fs = f + k - 1;
            if (fs >= 0 && fs < FR) {
                #pragma unroll
                for (int i = 0; i < CPG; ++i)
                    acc += ys[fs*FSTR + gi + i] * wreg[i][k];
            }
        }
        float pr = acc >= 0.0f ? acc : alpha*acc;
        out[obase + f*TT*CC + lane] = xs[f*FSTR + lane] + pr;
    }
}

extern "C" void kernel_launch(void* const* d_in, const int* in_sizes, int n_in,
                              void* d_out, int out_size, void* d_ws, size_t ws_size,
                              hipStream_t stream) {
    const float* h      = (const float*)d_in[0];
    const float* fc1_g  = (const float*)d_in[1];
    const float* fc1_b  = (const float*)d_in[2];
    const float* fc1_w  = (const float*)d_in[3];
    const float* fc1_cb = (const float*)d_in[4];
    const float* fc1_a  = (const float*)d_in[5];
    const float* fbl_g  = (const float*)d_in[6];
    const float* fbl_b  = (const float*)d_in[7];
    const float* red_w  = (const float*)d_in[8];
    const float* red_b  = (const float*)d_in[9];
    const float* fW     = (const float*)d_in[10];
    const float* fB     = (const float*)d_in[11];
    const float* exp_w  = (const float*)d_in[12];
    const float* exp_b  = (const float*)d_in[13];
    const float* fc2_g  = (const float*)d_in[14];
    const float* fc2_b  = (const float*)d_in[15];
    const float* fc2_w  = (const float*)d_in[16];
    const float* fc2_cb = (const float*)d_in[17];
    const float* fc2_a  = (const float*)d_in[18];

    float* ws   = (float*)d_ws;
    float* x1   = ws;
    float* hpT  = x1 + X1_ELEMS;
    float* hp2T = hpT + HP_ELEMS;

    k_fc1<<<NN, 256, 0, stream>>>(h, fc1_g, fc1_b, fc1_w, fc1_cb, fc1_a,
                                  fbl_g, fbl_b, red_w, red_b, x1, hpT);

    dim3 g2((NN + BM - 1)/BM, (FR + BN - 1)/BN, CPPC);
    k_fgemm<<<g2, 256, 0, stream>>>(hpT, fW, fB, hp2T);

    k_fc2<<<NN, 256, 0, stream>>>(x1, hp2T, exp_w, exp_b,
                                  fc2_g, fc2_b, fc2_w, fc2_cb, fc2_a,
                                  (float*)d_out);
}